// Round 13
// baseline (455.363 us; speedup 1.0000x reference)
//
#include <hip/hip_runtime.h>

typedef short short8 __attribute__((ext_vector_type(8)));
typedef float f32x4 __attribute__((ext_vector_type(4)));
typedef unsigned short ushort_t;

__device__ __forceinline__ unsigned short f2bf(float f){
  unsigned int u = __builtin_bit_cast(unsigned int, f);
  u += 0x7FFFu + ((u >> 16) & 1u);
  return (unsigned short)(u >> 16);
}
__device__ __forceinline__ float bf2f(unsigned short u){
  return __builtin_bit_cast(float, ((unsigned int)u) << 16);
}
__device__ __forceinline__ void gload_lds16(const void* g, void* l){
  __builtin_amdgcn_global_load_lds((const __attribute__((address_space(1))) unsigned int*)g,
                                   (__attribute__((address_space(3))) unsigned int*)l, 16, 0, 0);
}

// ---------------- elementwise casts ----------------
__global__ __launch_bounds__(256) void cast_bf16_kernel(const float* __restrict__ in,
                                                        ushort_t* __restrict__ out, long n4){
  long i = (long)blockIdx.x*256 + threadIdx.x;
  if (i >= n4) return;
  const float4 v = reinterpret_cast<const float4*>(in)[i];
  ushort4 o; o.x=f2bf(v.x); o.y=f2bf(v.y); o.z=f2bf(v.z); o.w=f2bf(v.w);
  reinterpret_cast<ushort4*>(out)[i] = o;
}

__global__ __launch_bounds__(256) void cast4_bf16_kernel(const float* __restrict__ w0, const float* __restrict__ w1,
                                                         const float* __restrict__ w2, const float* __restrict__ w3,
                                                         ushort_t* __restrict__ o0, ushort_t* __restrict__ o1,
                                                         ushort_t* __restrict__ o2, ushort_t* __restrict__ o3,
                                                         long n4){
  long i = (long)blockIdx.x*256 + threadIdx.x;
  if (i >= n4) return;
  const float* in; ushort_t* out;
  switch (blockIdx.y){
    case 0: in = w0; out = o0; break;
    case 1: in = w1; out = o1; break;
    case 2: in = w2; out = o2; break;
    default: in = w3; out = o3; break;
  }
  const float4 v = reinterpret_cast<const float4*>(in)[i];
  ushort4 o; o.x=f2bf(v.x); o.y=f2bf(v.y); o.z=f2bf(v.z); o.w=f2bf(v.w);
  reinterpret_cast<ushort4*>(out)[i] = o;
}

// ---------------- in-place RoPE on bf16 (Q and K in one dispatch) ----------------
// Q scale = 1/sqrt(128) * log2(e)  (exp2-folded softmax)
__global__ __launch_bounds__(256) void rope2_kernel(ushort_t* __restrict__ Qs,
                                                    ushort_t* __restrict__ Ks,
                                                    const float* __restrict__ cosb,
                                                    const float* __restrict__ sinb){
  long idx = (long)blockIdx.x*256 + threadIdx.x;
  ushort_t* X = blockIdx.y ? Ks : Qs;
  const float scale = blockIdx.y ? 1.0f : 0.12751744726f;
  int dq = (int)(idx & 15);
  long rest = idx >> 4;
  int h = (int)(rest & 15); rest >>= 4;
  int s = (int)(rest & 2047);
  int b = (int)(rest >> 11);
  long base = ((long)(b*2048 + s))*2048 + h*128;
  int d0 = dq*4;
  ushort4 x1 = *(const ushort4*)&X[base + d0];
  ushort4 x2 = *(const ushort4*)&X[base + 64 + d0];
  float4 cc = *(const float4*)&cosb[s*64 + d0];
  float4 ss = *(const float4*)&sinb[s*64 + d0];
  ushort4 o1, o2;
  { float a=bf2f(x1.x), bb=bf2f(x2.x); o1.x=f2bf((a*cc.x-bb*ss.x)*scale); o2.x=f2bf((a*ss.x+bb*cc.x)*scale); }
  { float a=bf2f(x1.y), bb=bf2f(x2.y); o1.y=f2bf((a*cc.y-bb*ss.y)*scale); o2.y=f2bf((a*ss.y+bb*cc.y)*scale); }
  { float a=bf2f(x1.z), bb=bf2f(x2.z); o1.z=f2bf((a*cc.z-bb*ss.z)*scale); o2.z=f2bf((a*ss.z+bb*cc.z)*scale); }
  { float a=bf2f(x1.w), bb=bf2f(x2.w); o1.w=f2bf((a*cc.w-bb*ss.w)*scale); o2.w=f2bf((a*ss.w+bb*cc.w)*scale); }
  *(ushort4*)&X[base + d0] = o1;
  *(ushort4*)&X[base + 64 + d0] = o2;
}

// ================= 8-phase 256x256 NT GEMM, QKV fused =================
// r10 guard structure + ONE-PHASE-AHEAD fragment reads (placed AFTER each
// phase's VM+BAR so they inherit the same visibility guards).
// Consumption: ph1{aR,b0} ph2{aR,b1} ph3{aR2,b0} ph4{aR2,b1} (buf0), ph5-8 same (buf1).
// Reads (early): pre{aR,b0} ph1{b1} ph2{aR2} ph4{aR',b0'} ph5{b1'} ph6{aR2'} ph8{aR'',b0''}.
// Reuse gaps >= 1 phase -> single register set suffices.

#define LDA8(DST, P, QM) do{ \
  _Pragma("unroll") for (int i_ = 0; i_ < 4; ++i_){ \
    DST[i_][0] = *(const short8*)&lA[(P)*16384 + ((QM)*128 + aRowBase + i_*16)*64 + sw0]; \
    DST[i_][1] = *(const short8*)&lA[(P)*16384 + ((QM)*128 + aRowBase + i_*16)*64 + sw1]; } }while(0)

#define LDB4(DST, P, BH) do{ \
  _Pragma("unroll") for (int j_ = 0; j_ < 2; ++j_){ \
    DST[j_][0] = *(const short8*)&lB[(P)*16384 + ((BH)*128 + bRowBase + j_*16)*64 + sw0]; \
    DST[j_][1] = *(const short8*)&lB[(P)*16384 + ((BH)*128 + bRowBase + j_*16)*64 + sw1]; } }while(0)

#define STAGE_A(P, QM, T) do{ \
  gload_lds16(aS0 + (long)(QM)*64*K + (long)(T)*64, &lA[(P)*16384 + (QM)*8192 + tid*8]); \
  gload_lds16(aS1 + (long)(QM)*64*K + (long)(T)*64, &lA[(P)*16384 + (QM)*8192 + 4096 + tid*8]); }while(0)

#define STAGE_B(P, QN, T) do{ \
  gload_lds16(bS0 + (long)(QN)*32*K + (long)(T)*64, &lB[(P)*16384 + (QN)*8192 + tid*8]); \
  gload_lds16(bS1 + (long)(QN)*32*K + (long)(T)*64, &lB[(P)*16384 + (QN)*8192 + 4096 + tid*8]); }while(0)

#define MFK(QM, BH, AR, BR) do{ \
  __builtin_amdgcn_s_setprio(1); \
  _Pragma("unroll") for (int k_ = 0; k_ < 2; ++k_) \
    _Pragma("unroll") for (int i_ = 0; i_ < 4; ++i_) \
      _Pragma("unroll") for (int j_ = 0; j_ < 2; ++j_) \
        acc[(QM)*4+i_][(BH)*2+j_] = __builtin_amdgcn_mfma_f32_16x16x32_bf16(AR[i_][k_], BR[j_][k_], acc[(QM)*4+i_][(BH)*2+j_], 0, 0, 0); \
  __builtin_amdgcn_s_setprio(0); }while(0)

#define BAR() do{ __builtin_amdgcn_s_barrier(); asm volatile("" ::: "memory"); }while(0)
#define VM(N) asm volatile("s_waitcnt vmcnt(" #N ")" ::: "memory")

__global__ __launch_bounds__(512, 2) void gemm_qkv_8ph(const ushort_t* __restrict__ A,
                                                       const ushort_t* __restrict__ Bw,
                                                       ushort_t* __restrict__ Cq,
                                                       ushort_t* __restrict__ Ck,
                                                       ushort_t* __restrict__ Vt,
                                                       int MT, int K){
  __shared__ ushort_t lA[32768];
  __shared__ ushort_t lB[32768];
  const int tid = threadIdx.x;
  const int lane = tid & 63, wid = tid >> 6;
  const int g = lane >> 4, c = lane & 15;
  const int wm = wid >> 2, wn = wid & 3;

  const int nwg = (int)gridDim.x, cpx = nwg >> 3;
  int sw = (blockIdx.x & 7)*cpx + (blockIdx.x >> 3);
  const long m0 = (long)(sw % MT)*256;
  const long n0 = (long)(sw / MT)*256;

  const int prl0 = tid >> 3, q1 = 512 + tid, prl1 = q1 >> 3;
  const int sl0 = ((tid & 7) ^ (prl0 & 7)) * 8;
  const int sl1 = ((q1 & 7) ^ (prl1 & 7)) * 8;
  const int rowA0 = ((prl0 >> 6)*128) + (prl0 & 63);
  const int rowA1 = ((prl1 >> 6)*128) + (prl1 & 63);
  const int rowB0 = ((prl0 >> 5)*64) + (prl0 & 31);
  const int rowB1 = ((prl1 >> 5)*64) + (prl1 & 31);
  const ushort_t* aS0 = A + (m0 + rowA0)*K + sl0;
  const ushort_t* aS1 = A + (m0 + rowA1)*K + sl1;
  const ushort_t* bS0 = Bw + (n0 + rowB0)*K + sl0;
  const ushort_t* bS1 = Bw + (n0 + rowB1)*K + sl1;

  const int sw0 = (g ^ (c & 7)) * 8;
  const int sw1 = ((4 + g) ^ (c & 7)) * 8;
  const int aRowBase = wm*64 + c;
  const int bRowBase = wn*32 + c;

  f32x4 acc[8][4] = {};
  short8 aR[4][2], aR2[4][2], b0[2][2], b1[2][2];
  const int NI = K >> 7;

  // prologue: t0 full (buf0) + t1 first 3 halves (buf1)
  STAGE_A(0, 0, 0); STAGE_B(0, 0, 0);
  STAGE_B(0, 1, 0); STAGE_A(0, 1, 0);
  STAGE_A(1, 0, 1); STAGE_B(1, 0, 1); STAGE_B(1, 1, 1);
  VM(6);
  BAR();
  LDA8(aR, 0, 0); LDB4(b0, 0, 0);   // frags for ph1

  for (int j = 0; j < NI-1; ++j){
    const int t = 2*j;
    /*ph1*/ STAGE_A(1, 1, t+1); BAR(); LDB4(b1, 0, 1);                  MFK(0, 0, aR, b0);  BAR();
    /*ph2*/ STAGE_A(0, 0, t+2); BAR(); LDA8(aR2, 0, 1);                 MFK(0, 1, aR, b1);  BAR();
    /*ph3*/ STAGE_B(0, 0, t+2); BAR();                                  MFK(1, 0, aR2, b0); BAR();
    /*ph4*/ VM(4); STAGE_B(0, 1, t+2); BAR(); LDA8(aR, 1, 0); LDB4(b0, 1, 0); MFK(1, 1, aR2, b1); BAR();
    /*ph5*/ STAGE_A(0, 1, t+2); BAR(); LDB4(b1, 1, 1);                  MFK(0, 0, aR, b0);  BAR();
    /*ph6*/ STAGE_A(1, 0, t+3); BAR(); LDA8(aR2, 1, 1);                 MFK(0, 1, aR, b1);  BAR();
    /*ph7*/ STAGE_B(1, 0, t+3); BAR();                                  MFK(1, 0, aR2, b0); BAR();
    /*ph8*/ VM(4); STAGE_B(1, 1, t+3); BAR(); LDA8(aR, 0, 0); LDB4(b0, 0, 0); MFK(1, 1, aR2, b1); BAR();
  }
  { // tail iteration: only ph1's stage remains; full drain at ph4
    /*ph1*/ STAGE_A(1, 1, 2*(NI-1)+1); BAR(); LDB4(b1, 0, 1);           MFK(0, 0, aR, b0);  BAR();
    /*ph2*/ BAR(); LDA8(aR2, 0, 1);                                     MFK(0, 1, aR, b1);  BAR();
    /*ph3*/ BAR();                                                      MFK(1, 0, aR2, b0); BAR();
    /*ph4*/ VM(0); BAR(); LDA8(aR, 1, 0); LDB4(b0, 1, 0);               MFK(1, 1, aR2, b1); BAR();
    /*ph5*/ BAR(); LDB4(b1, 1, 1);                                      MFK(0, 0, aR, b0);  BAR();
    /*ph6*/ BAR(); LDA8(aR2, 1, 1);                                     MFK(0, 1, aR, b1);  BAR();
    /*ph7*/ BAR();                                                      MFK(1, 0, aR2, b0); BAR();
    /*ph8*/ BAR();                                                      MFK(1, 1, aR2, b1); BAR();
  }

  const long rbase = m0 + wm*128 + g*4;
  const long cbase = n0 + wn*64 + c;
  const int third = (int)(n0 >> 11);
  if (third < 2){
    ushort_t* dst = (third == 0) ? Cq : Ck;
    const long csub = cbase - (long)third*2048;
#pragma unroll
    for (int mi = 0; mi < 8; ++mi)
#pragma unroll
      for (int ni = 0; ni < 4; ++ni){
        long off = (rbase + mi*16)*2048 + csub + ni*16;
#pragma unroll
        for (int r = 0; r < 4; ++r)
          dst[off + (long)r*2048] = f2bf(acc[mi][ni][r]);
      }
  } else {
#pragma unroll
    for (int mi = 0; mi < 8; ++mi){
      const long row = rbase + mi*16;
      const long s = row & 2047, bb = row >> 11;
#pragma unroll
      for (int ni = 0; ni < 4; ++ni){
        long hd = cbase + ni*16 - 4096;
        long vaddr = ((bb*16 + (hd >> 7))*128 + (hd & 127))*2048 + s;
        ushort4 o4;
        o4.x = f2bf(acc[mi][ni][0]); o4.y = f2bf(acc[mi][ni][1]);
        o4.z = f2bf(acc[mi][ni][2]); o4.w = f2bf(acc[mi][ni][3]);
        *(ushort4*)&Vt[vaddr] = o4;
      }
    }
  }
}

// ---------------- m97-style NT GEMM (WO): C f32 ----------------
__global__ __launch_bounds__(256) void gemm_nt_lds(const ushort_t* __restrict__ A,
                                                   const ushort_t* __restrict__ B,
                                                   float* __restrict__ C,
                                                   int M, int N, int K){
  const int tid = threadIdx.x;
  const int l = tid & 63;
  const int g = l >> 4, c = l & 15;
  const int w = tid >> 6, wr = w >> 1, wc = w & 1;
  const long m0 = (long)blockIdx.x*128, n0 = (long)blockIdx.y*128;
  __shared__ ushort_t lds_a[128*32];
  __shared__ ushort_t lds_b[128*32];
  f32x4 acc[4][4] = {};
  const int q1 = tid, q2 = 256 + tid;
  const ushort_t* a1 = A + (m0 + (q1>>2))*(long)K + (q1&3)*8;
  const ushort_t* a2 = A + (m0 + (q2>>2))*(long)K + (q2&3)*8;
  const ushort_t* b1 = B + (n0 + (q1>>2))*(long)K + (q1&3)*8;
  const ushort_t* b2 = B + (n0 + (q2>>2))*(long)K + (q2&3)*8;
  for (int k0 = 0; k0 < K; k0 += 32){
    __syncthreads();
    gload_lds16(a1 + k0, &lds_a[q1*8]);
    gload_lds16(a2 + k0, &lds_a[q2*8]);
    gload_lds16(b1 + k0, &lds_b[q1*8]);
    gload_lds16(b2 + k0, &lds_b[q2*8]);
    __syncthreads();
    short8 af[4], bf[4];
#pragma unroll
    for (int i = 0; i < 4; ++i) af[i] = *(const short8*)&lds_a[(wr*64 + i*16 + c)*32 + g*8];
#pragma unroll
    for (int j = 0; j < 4; ++j) bf[j] = *(const short8*)&lds_b[(wc*64 + j*16 + c)*32 + g*8];
#pragma unroll
    for (int i = 0; i < 4; ++i)
#pragma unroll
      for (int j = 0; j < 4; ++j)
        acc[i][j] = __builtin_amdgcn_mfma_f32_16x16x32_bf16(af[i], bf[j], acc[i][j], 0, 0, 0);
  }
#pragma unroll
  for (int i = 0; i < 4; ++i)
#pragma unroll
    for (int j = 0; j < 4; ++j)
#pragma unroll
      for (int r = 0; r < 4; ++r)
        C[(m0 + wr*64 + i*16 + g*4 + r)*(long)N + n0 + wc*64 + j*16 + c] = acc[i][j][r];
}

// ---------------- flash attention: r10 structure + exp2 (scalar f2bf P-pack) ----------------
__global__ __launch_bounds__(256) void attn_kernel(const ushort_t* __restrict__ Q,
                                                   const ushort_t* __restrict__ Kr,
                                                   const ushort_t* __restrict__ Vt,
                                                   ushort_t* __restrict__ O){
  const int tid = threadIdx.x;
  const int l = tid & 63, w = tid >> 6;
  const int g = l >> 4, c = l & 15;
  const int bh = blockIdx.x;
  const int qt = (int)gridDim.y - 1 - (int)blockIdx.y;
  const int b = bh >> 4, h = bh & 15;
  const int q0 = qt * 64;
  const int qw0 = q0 + w * 16;
  const int nt = qt + 1;

  __shared__ ushort_t k_lds[2][64*128];
  __shared__ ushort_t v_lds[2][128*64];
  __shared__ ushort_t p_lds[4][16*72];

  short8 qf[4];
  const long qbase = ((long)(b*2048 + qw0 + c))*2048 + h*128 + g*8;
#pragma unroll
  for (int ds = 0; ds < 4; ++ds) qf[ds] = *(const short8*)(Q + qbase + ds*32);

  const ushort_t* ksrc[4]; const ushort_t* vsrc[4];
  int kof[4], vof[4];
#pragma unroll
  for (int i = 0; i < 4; ++i){
    int q = i*256 + tid;
    int r = q >> 4, j = q & 15;
    ksrc[i] = Kr + ((long)(b*2048 + r))*2048 + h*128 + (j ^ (r & 7))*8;
    kof[i] = q*8;
    int d = q >> 3, jj = q & 7;
    vsrc[i] = Vt + ((long)(bh*128 + d))*2048 + (jj ^ (d & 7))*8;
    vof[i] = q*8;
  }

  f32x4 o[8] = {};
  float m = -1e30f, lsum = 0.f;
  const int sw = (c & 7) << 3;

#pragma unroll
  for (int i = 0; i < 4; ++i) gload_lds16(ksrc[i], &k_lds[0][kof[i]]);
#pragma unroll
  for (int i = 0; i < 4; ++i) gload_lds16(vsrc[i], &v_lds[0][vof[i]]);
  __syncthreads();

  for (int t = 0; t < nt; ++t){
    const int p = t & 1;
    if (t + 1 < nt){
#pragma unroll
      for (int i = 0; i < 4; ++i)
        gload_lds16(ksrc[i] + (long)(t+1)*64*2048, &k_lds[p^1][kof[i]]);
#pragma unroll
      for (int i = 0; i < 4; ++i)
        gload_lds16(vsrc[i] + (t+1)*64, &v_lds[p^1][vof[i]]);
    }
    const int kv0 = t*64;

    f32x4 s[4] = {};
    __builtin_amdgcn_s_setprio(1);
#pragma unroll
    for (int t4 = 0; t4 < 4; ++t4){
      const int row = 16*t4 + c;
#pragma unroll
      for (int ds = 0; ds < 4; ++ds){
        short8 kf = *(const short8*)&k_lds[p][(row*128 + ds*32 + g*8) ^ sw];
        s[t4] = __builtin_amdgcn_mfma_f32_16x16x32_bf16(kf, qf[ds], s[t4], 0, 0, 0);
      }
    }
    __builtin_amdgcn_s_setprio(0);
    if (kv0 + 63 > qw0){
      const int qg = qw0 + c;
#pragma unroll
      for (int t4 = 0; t4 < 4; ++t4)
#pragma unroll
        for (int r = 0; r < 4; ++r)
          if (kv0 + 16*t4 + 4*g + r > qg) s[t4][r] = -1e30f;
    }
    float tm = -1e30f;
#pragma unroll
    for (int t4 = 0; t4 < 4; ++t4)
      tm = fmaxf(tm, fmaxf(fmaxf(s[t4][0], s[t4][1]), fmaxf(s[t4][2], s[t4][3])));
    tm = fmaxf(tm, __shfl_xor(tm, 16, 64));
    tm = fmaxf(tm, __shfl_xor(tm, 32, 64));
    if (!__all(tm <= m + 11.5f)){
      float mn = fmaxf(m, tm);
      float al = exp2f(m - mn);
      m = mn;
      lsum *= al;
      float alr[4];
#pragma unroll
      for (int r = 0; r < 4; ++r) alr[r] = __shfl(al, 4*g + r, 64);
#pragma unroll
      for (int dt = 0; dt < 8; ++dt)
#pragma unroll
        for (int r = 0; r < 4; ++r) o[dt][r] *= alr[r];
    }
    float ps = 0.f;
#pragma unroll
    for (int t4 = 0; t4 < 4; ++t4)
#pragma unroll
      for (int r = 0; r < 4; ++r){ float pex = exp2f(s[t4][r] - m); s[t4][r] = pex; ps += pex; }
    ps += __shfl_xor(ps, 16, 64);
    ps += __shfl_xor(ps, 32, 64);
    lsum += ps;
#pragma unroll
    for (int t4 = 0; t4 < 4; ++t4){
      uint2 pw;
      pw.x = (unsigned)f2bf(s[t4][0]) | ((unsigned)f2bf(s[t4][1]) << 16);
      pw.y = (unsigned)f2bf(s[t4][2]) | ((unsigned)f2bf(s[t4][3]) << 16);
      *reinterpret_cast<uint2*>(&p_lds[w][c*72 + 16*t4 + 4*g]) = pw;
    }
    __builtin_amdgcn_s_setprio(1);
#pragma unroll
    for (int kc = 0; kc < 2; ++kc){
      short8 pf = *(const short8*)&p_lds[w][c*72 + 32*kc + 8*g];
#pragma unroll
      for (int dt = 0; dt < 8; ++dt){
        short8 vf = *(const short8*)&v_lds[p][(((16*dt + c)*64) + kc*32 + g*8) ^ sw];
        o[dt] = __builtin_amdgcn_mfma_f32_16x16x32_bf16(pf, vf, o[dt], 0, 0, 0);
      }
    }
    __builtin_amdgcn_s_setprio(0);
    __syncthreads();
  }

  float inv = 1.f / lsum;
  float invr[4];
#pragma unroll
  for (int r = 0; r < 4; ++r) invr[r] = __shfl(inv, 4*g + r, 64);
  const long obase = ((long)(b*2048 + qw0 + g*4))*2048 + h*128 + c;
#pragma unroll
  for (int dt = 0; dt < 8; ++dt)
#pragma unroll
    for (int r = 0; r < 4; ++r)
      O[obase + (long)r*2048 + dt*16] = f2bf(o[dt][r] * invr[r]);
}

// ---------------- launcher ----------------
extern "C" void kernel_launch(void* const* d_in, const int* in_sizes, int n_in,
                              void* d_out, int out_size, void* d_ws, size_t ws_size,
                              hipStream_t stream){
  const float* x    = (const float*)d_in[0];
  const float* cosb = (const float*)d_in[1];
  const float* sinb = (const float*)d_in[2];
  const float* wq   = (const float*)d_in[3];
  const float* wk   = (const float*)d_in[4];
  const float* wv   = (const float*)d_in[5];
  const float* wo   = (const float*)d_in[6];
  float* out = (float*)d_out;

  const int S = 2048, DIM = 2048;
  const long MN = 4096;

  char* ws = (char*)d_ws;
  ushort_t* xb     = (ushort_t*)(ws);                 // 16MB
  ushort_t* wqkvb  = (ushort_t*)(ws + (16l<<20));     // 24MB
  ushort_t* wob    = (ushort_t*)(ws + (40l<<20));     // 8MB
  ushort_t* qstage = (ushort_t*)(ws + (48l<<20));     // 16MB
  ushort_t* kstage = (ushort_t*)(ws + (64l<<20));     // 16MB
  ushort_t* attnb  = (ushort_t*)(ws + (80l<<20));     // 16MB
  ushort_t* vt     = (ushort_t*)(ws + (96l<<20));     // 16MB -> 112MB total

  const long xn4 = MN*DIM/4, wn4 = (long)DIM*DIM/4;
  cast_bf16_kernel<<<(int)((xn4+255)/256), 256, 0, stream>>>(x, xb, xn4);
  cast4_bf16_kernel<<<dim3((int)((wn4+255)/256), 4), 256, 0, stream>>>(
      wq, wk, wv, wo,
      wqkvb, wqkvb + 4194304, wqkvb + 8388608, wob, wn4);

  gemm_qkv_8ph<<<(MN/256)*(6144/256), 512, 0, stream>>>(
      xb, wqkvb, qstage, kstage, vt, (int)(MN/256), DIM);

  const int ropeBlocks = (2*2048*16*16)/256;
  rope2_kernel<<<dim3(ropeBlocks, 2), 256, 0, stream>>>(qstage, kstage, cosb, sinb);
  attn_kernel<<<dim3(32, S/64), 256, 0, stream>>>(qstage, kstage, vt, attnb);
  gemm_nt_lds<<<dim3(MN/128, DIM/128), 256, 0, stream>>>(attnb, wob, out, (int)MN, DIM, DIM);
}

// Round 15
// 275.153 us; speedup vs baseline: 1.6549x; 1.6549x over previous
//
#include <hip/hip_runtime.h>

typedef short short8 __attribute__((ext_vector_type(8)));
typedef float f32x4 __attribute__((ext_vector_type(4)));
typedef unsigned short ushort_t;

__device__ __forceinline__ unsigned short f2bf(float f){
  unsigned int u = __builtin_bit_cast(unsigned int, f);
  u += 0x7FFFu + ((u >> 16) & 1u);
  return (unsigned short)(u >> 16);
}
__device__ __forceinline__ float bf2f(unsigned short u){
  return __builtin_bit_cast(float, ((unsigned int)u) << 16);
}
__device__ __forceinline__ void gload_lds16(const void* g, void* l){
  __builtin_amdgcn_global_load_lds((const __attribute__((address_space(1))) unsigned int*)g,
                                   (__attribute__((address_space(3))) unsigned int*)l, 16, 0, 0);
}

// ---------------- elementwise casts ----------------
__global__ __launch_bounds__(256) void cast_bf16_kernel(const float* __restrict__ in,
                                                        ushort_t* __restrict__ out, long n4){
  long i = (long)blockIdx.x*256 + threadIdx.x;
  if (i >= n4) return;
  const float4 v = reinterpret_cast<const float4*>(in)[i];
  ushort4 o; o.x=f2bf(v.x); o.y=f2bf(v.y); o.z=f2bf(v.z); o.w=f2bf(v.w);
  reinterpret_cast<ushort4*>(out)[i] = o;
}

__global__ __launch_bounds__(256) void cast4_bf16_kernel(const float* __restrict__ w0, const float* __restrict__ w1,
                                                         const float* __restrict__ w2, const float* __restrict__ w3,
                                                         ushort_t* __restrict__ o0, ushort_t* __restrict__ o1,
                                                         ushort_t* __restrict__ o2, ushort_t* __restrict__ o3,
                                                         long n4){
  long i = (long)blockIdx.x*256 + threadIdx.x;
  if (i >= n4) return;
  const float* in; ushort_t* out;
  switch (blockIdx.y){
    case 0: in = w0; out = o0; break;
    case 1: in = w1; out = o1; break;
    case 2: in = w2; out = o2; break;
    default: in = w3; out = o3; break;
  }
  const float4 v = reinterpret_cast<const float4*>(in)[i];
  ushort4 o; o.x=f2bf(v.x); o.y=f2bf(v.y); o.z=f2bf(v.z); o.w=f2bf(v.w);
  reinterpret_cast<ushort4*>(out)[i] = o;
}

// ---------------- in-place RoPE on bf16 (Q and K in one dispatch) ----------------
__global__ __launch_bounds__(256) void rope2_kernel(ushort_t* __restrict__ Qs,
                                                    ushort_t* __restrict__ Ks,
                                                    const float* __restrict__ cosb,
                                                    const float* __restrict__ sinb){
  long idx = (long)blockIdx.x*256 + threadIdx.x;
  ushort_t* X = blockIdx.y ? Ks : Qs;
  const float scale = blockIdx.y ? 1.0f : 0.08838834764831845f;
  int dq = (int)(idx & 15);
  long rest = idx >> 4;
  int h = (int)(rest & 15); rest >>= 4;
  int s = (int)(rest & 2047);
  int b = (int)(rest >> 11);
  long base = ((long)(b*2048 + s))*2048 + h*128;
  int d0 = dq*4;
  ushort4 x1 = *(const ushort4*)&X[base + d0];
  ushort4 x2 = *(const ushort4*)&X[base + 64 + d0];
  float4 cc = *(const float4*)&cosb[s*64 + d0];
  float4 ss = *(const float4*)&sinb[s*64 + d0];
  ushort4 o1, o2;
  { float a=bf2f(x1.x), bb=bf2f(x2.x); o1.x=f2bf((a*cc.x-bb*ss.x)*scale); o2.x=f2bf((a*ss.x+bb*cc.x)*scale); }
  { float a=bf2f(x1.y), bb=bf2f(x2.y); o1.y=f2bf((a*cc.y-bb*ss.y)*scale); o2.y=f2bf((a*ss.y+bb*cc.y)*scale); }
  { float a=bf2f(x1.z), bb=bf2f(x2.z); o1.z=f2bf((a*cc.z-bb*ss.z)*scale); o2.z=f2bf((a*ss.z+bb*cc.z)*scale); }
  { float a=bf2f(x1.w), bb=bf2f(x2.w); o1.w=f2bf((a*cc.w-bb*ss.w)*scale); o2.w=f2bf((a*ss.w+bb*cc.w)*scale); }
  *(ushort4*)&X[base + d0] = o1;
  *(ushort4*)&X[base + 64 + d0] = o2;
}

// ================= 8-phase 256x256 NT GEMM, QKV fused (verified r10/r12, 137.6us) =================
#define LDA8(DST, P, QM) do{ \
  _Pragma("unroll") for (int i_ = 0; i_ < 4; ++i_){ \
    DST[i_][0] = *(const short8*)&lA[(P)*16384 + ((QM)*128 + aRowBase + i_*16)*64 + sw0]; \
    DST[i_][1] = *(const short8*)&lA[(P)*16384 + ((QM)*128 + aRowBase + i_*16)*64 + sw1]; } }while(0)

#define LDB4(DST, P, BH) do{ \
  _Pragma("unroll") for (int j_ = 0; j_ < 2; ++j_){ \
    DST[j_][0] = *(const short8*)&lB[(P)*16384 + ((BH)*128 + bRowBase + j_*16)*64 + sw0]; \
    DST[j_][1] = *(const short8*)&lB[(P)*16384 + ((BH)*128 + bRowBase + j_*16)*64 + sw1]; } }while(0)

#define STAGE_A(P, QM, T) do{ \
  gload_lds16(aS0 + (long)(QM)*64*K + (long)(T)*64, &lA[(P)*16384 + (QM)*8192 + tid*8]); \
  gload_lds16(aS1 + (long)(QM)*64*K + (long)(T)*64, &lA[(P)*16384 + (QM)*8192 + 4096 + tid*8]); }while(0)

#define STAGE_B(P, QN, T) do{ \
  gload_lds16(bS0 + (long)(QN)*32*K + (long)(T)*64, &lB[(P)*16384 + (QN)*8192 + tid*8]); \
  gload_lds16(bS1 + (long)(QN)*32*K + (long)(T)*64, &lB[(P)*16384 + (QN)*8192 + 4096 + tid*8]); }while(0)

#define MFK(QM, BH, AR, BR) do{ \
  __builtin_amdgcn_s_setprio(1); \
  _Pragma("unroll") for (int k_ = 0; k_ < 2; ++k_) \
    _Pragma("unroll") for (int i_ = 0; i_ < 4; ++i_) \
      _Pragma("unroll") for (int j_ = 0; j_ < 2; ++j_) \
        acc[(QM)*4+i_][(BH)*2+j_] = __builtin_amdgcn_mfma_f32_16x16x32_bf16(AR[i_][k_], BR[j_][k_], acc[(QM)*4+i_][(BH)*2+j_], 0, 0, 0); \
  __builtin_amdgcn_s_setprio(0); }while(0)

#define BAR() do{ __builtin_amdgcn_s_barrier(); asm volatile("" ::: "memory"); }while(0)
#define VM(N) asm volatile("s_waitcnt vmcnt(" #N ")" ::: "memory")

__global__ __launch_bounds__(512, 2) void gemm_qkv_8ph(const ushort_t* __restrict__ A,
                                                       const ushort_t* __restrict__ Bw,
                                                       ushort_t* __restrict__ Cq,
                                                       ushort_t* __restrict__ Ck,
                                                       ushort_t* __restrict__ Vt,
                                                       int MT, int K){
  __shared__ ushort_t lA[32768];
  __shared__ ushort_t lB[32768];
  const int tid = threadIdx.x;
  const int lane = tid & 63, wid = tid >> 6;
  const int g = lane >> 4, c = lane & 15;
  const int wm = wid >> 2, wn = wid & 3;

  const int nwg = (int)gridDim.x, cpx = nwg >> 3;
  int sw = (blockIdx.x & 7)*cpx + (blockIdx.x >> 3);
  const long m0 = (long)(sw % MT)*256;
  const long n0 = (long)(sw / MT)*256;

  const int prl0 = tid >> 3, q1 = 512 + tid, prl1 = q1 >> 3;
  const int sl0 = ((tid & 7) ^ (prl0 & 7)) * 8;
  const int sl1 = ((q1 & 7) ^ (prl1 & 7)) * 8;
  const int rowA0 = ((prl0 >> 6)*128) + (prl0 & 63);
  const int rowA1 = ((prl1 >> 6)*128) + (prl1 & 63);
  const int rowB0 = ((prl0 >> 5)*64) + (prl0 & 31);
  const int rowB1 = ((prl1 >> 5)*64) + (prl1 & 31);
  const ushort_t* aS0 = A + (m0 + rowA0)*K + sl0;
  const ushort_t* aS1 = A + (m0 + rowA1)*K + sl1;
  const ushort_t* bS0 = Bw + (n0 + rowB0)*K + sl0;
  const ushort_t* bS1 = Bw + (n0 + rowB1)*K + sl1;

  const int sw0 = (g ^ (c & 7)) * 8;
  const int sw1 = ((4 + g) ^ (c & 7)) * 8;
  const int aRowBase = wm*64 + c;
  const int bRowBase = wn*32 + c;

  f32x4 acc[8][4] = {};
  short8 aR[4][2], aR2[4][2], b0[2][2], b1[2][2];
  const int NI = K >> 7;

  STAGE_A(0, 0, 0); STAGE_B(0, 0, 0);
  STAGE_B(0, 1, 0); STAGE_A(0, 1, 0);
  STAGE_A(1, 0, 1); STAGE_B(1, 0, 1); STAGE_B(1, 1, 1);
  VM(6);
  BAR();

  for (int j = 0; j < NI-1; ++j){
    const int t = 2*j;
    /*ph1*/ LDA8(aR, 0, 0); LDB4(b0, 0, 0); STAGE_A(1, 1, t+1); BAR(); MFK(0, 0, aR, b0); BAR();
    /*ph2*/ LDB4(b1, 0, 1);                 STAGE_A(0, 0, t+2); BAR(); MFK(0, 1, aR, b1); BAR();
    /*ph3*/ LDA8(aR2, 0, 1);                STAGE_B(0, 0, t+2); BAR(); MFK(1, 0, aR2, b0); BAR();
    /*ph4*/ VM(4);                          STAGE_B(0, 1, t+2); BAR(); MFK(1, 1, aR2, b1); BAR();
    /*ph5*/ LDA8(aR, 1, 0); LDB4(b0, 1, 0); STAGE_A(0, 1, t+2); BAR(); MFK(0, 0, aR, b0); BAR();
    /*ph6*/ LDB4(b1, 1, 1);                 STAGE_A(1, 0, t+3); BAR(); MFK(0, 1, aR, b1); BAR();
    /*ph7*/ LDA8(aR2, 1, 1);                STAGE_B(1, 0, t+3); BAR(); MFK(1, 0, aR2, b0); BAR();
    /*ph8*/ VM(4);                          STAGE_B(1, 1, t+3); BAR(); MFK(1, 1, aR2, b1); BAR();
  }
  {
    const int t = 2*(NI-1);
    /*ph1*/ LDA8(aR, 0, 0); LDB4(b0, 0, 0); STAGE_A(1, 1, t+1); BAR(); MFK(0, 0, aR, b0); BAR();
    /*ph2*/ LDB4(b1, 0, 1);                                     BAR(); MFK(0, 1, aR, b1); BAR();
    /*ph3*/ LDA8(aR2, 0, 1);                                    BAR(); MFK(1, 0, aR2, b0); BAR();
    /*ph4*/ VM(0);                                              BAR(); MFK(1, 1, aR2, b1); BAR();
    /*ph5*/ LDA8(aR, 1, 0); LDB4(b0, 1, 0);                     BAR(); MFK(0, 0, aR, b0); BAR();
    /*ph6*/ LDB4(b1, 1, 1);                                     BAR(); MFK(0, 1, aR, b1); BAR();
    /*ph7*/ LDA8(aR2, 1, 1);                                    BAR(); MFK(1, 0, aR2, b0); BAR();
    /*ph8*/                                                     BAR(); MFK(1, 1, aR2, b1); BAR();
  }

  const long rbase = m0 + wm*128 + g*4;
  const long cbase = n0 + wn*64 + c;
  const int third = (int)(n0 >> 11);
  if (third < 2){
    ushort_t* dst = (third == 0) ? Cq : Ck;
    const long csub = cbase - (long)third*2048;
#pragma unroll
    for (int mi = 0; mi < 8; ++mi)
#pragma unroll
      for (int ni = 0; ni < 4; ++ni){
        long off = (rbase + mi*16)*2048 + csub + ni*16;
#pragma unroll
        for (int r = 0; r < 4; ++r)
          dst[off + (long)r*2048] = f2bf(acc[mi][ni][r]);
      }
  } else {
#pragma unroll
    for (int mi = 0; mi < 8; ++mi){
      const long row = rbase + mi*16;
      const long s = row & 2047, bb = row >> 11;
#pragma unroll
      for (int ni = 0; ni < 4; ++ni){
        long hd = cbase + ni*16 - 4096;
        long vaddr = ((bb*16 + (hd >> 7))*128 + (hd & 127))*2048 + s;
        ushort4 o4;
        o4.x = f2bf(acc[mi][ni][0]); o4.y = f2bf(acc[mi][ni][1]);
        o4.z = f2bf(acc[mi][ni][2]); o4.w = f2bf(acc[mi][ni][3]);
        *(ushort4*)&Vt[vaddr] = o4;
      }
    }
  }
}

// ================= 4-phase 128x256 NT GEMM (WO), race-fixed =================
// Stage placement (each >=1 barrier AFTER the region's last read):
//  ph1: stage buf1-B(t+1)   [buf1-B last read: prev ph4]
//  ph2: VM(0); stage buf0-A(t+2)   [buf0-A last read: ph1]   -> guards ph3 reads
//  ph3: stage buf0-B(t+2)   [buf0-B last read: ph2]
//  ph4: VM(0); stage buf1-A(t+3)   [buf1-A last read: ph3]   -> guards next ph1 reads
// Every staged region completes >=2 phases before its read and is VM+BAR guarded.

#define WLDA8(P) do{ \
  _Pragma("unroll") for (int i_ = 0; i_ < 4; ++i_){ \
    aF[i_][0] = *(const short8*)&lA[(P)*8192 + (wm*64 + i_*16 + c)*64 + sw0]; \
    aF[i_][1] = *(const short8*)&lA[(P)*8192 + (wm*64 + i_*16 + c)*64 + sw1]; } }while(0)

#define WLDB4(P, NH) do{ \
  _Pragma("unroll") for (int j_ = 0; j_ < 2; ++j_){ \
    bF[j_][0] = *(const short8*)&lB[(P)*16384 + (wn*64 + ((NH)*2+j_)*16 + c)*64 + sw0]; \
    bF[j_][1] = *(const short8*)&lB[(P)*16384 + (wn*64 + ((NH)*2+j_)*16 + c)*64 + sw1]; } }while(0)

#define WSTAGE_A(P, T) do{ \
  gload_lds16(aW + (long)(T)*64,          &lA[(P)*8192 + tid*8]); \
  gload_lds16(aW + 64l*K + (long)(T)*64,  &lA[(P)*8192 + 4096 + tid*8]); }while(0)

#define WSTAGE_B0(P, T) do{ \
  gload_lds16(bW + (long)(T)*64,          &lB[(P)*16384 + tid*8]); \
  gload_lds16(bW + 64l*K + (long)(T)*64,  &lB[(P)*16384 + 4096 + tid*8]); }while(0)

#define WSTAGE_B1(P, T) do{ \
  gload_lds16(bW + 128l*K + (long)(T)*64, &lB[(P)*16384 + 8192 + tid*8]); \
  gload_lds16(bW + 192l*K + (long)(T)*64, &lB[(P)*16384 + 12288 + tid*8]); }while(0)

#define WMF16(NH) do{ \
  __builtin_amdgcn_s_setprio(1); \
  _Pragma("unroll") for (int k_ = 0; k_ < 2; ++k_) \
    _Pragma("unroll") for (int i_ = 0; i_ < 4; ++i_) \
      _Pragma("unroll") for (int j_ = 0; j_ < 2; ++j_) \
        acc[i_][(NH)*2+j_] = __builtin_amdgcn_mfma_f32_16x16x32_bf16(aF[i_][k_], bF[j_][k_], acc[i_][(NH)*2+j_], 0, 0, 0); \
  __builtin_amdgcn_s_setprio(0); }while(0)

__global__ __launch_bounds__(512, 2) void gemm_wo_8ph(const ushort_t* __restrict__ A,
                                                      const ushort_t* __restrict__ Bw,
                                                      float* __restrict__ C,
                                                      int MT, int N, int K){
  __shared__ ushort_t lA[16384];   // 2 x 128x64
  __shared__ ushort_t lB[32768];   // 2 x 256x64
  const int tid = threadIdx.x;
  const int lane = tid & 63, wid = tid >> 6;
  const int g = lane >> 4, c = lane & 15;
  const int wm = wid >> 2, wn = wid & 3;   // 2M x 4N waves

  const int nwg = (int)gridDim.x, cpx = nwg >> 3;
  int sw = (blockIdx.x & 7)*cpx + (blockIdx.x >> 3);
  const long m0 = (long)(sw % MT)*128;
  const long n0 = (long)(sw / MT)*256;

  const int rr = tid >> 3;
  const int ss = ((tid & 7) ^ (rr & 7)) * 8;
  const ushort_t* aW = A + (m0 + rr)*K + ss;
  const ushort_t* bW = Bw + (n0 + rr)*K + ss;

  const int sw0 = (g ^ (c & 7)) * 8;
  const int sw1 = ((4 + g) ^ (c & 7)) * 8;

  f32x4 acc[4][4] = {};
  short8 aF[4][2], bF[2][2];
  const int NI = K >> 7;   // 2 K-tiles per iteration (NI >= 2)

  // prologue: t0 full -> buf0 (6 gloads), t1-A -> buf1 (2); drain t0
  WSTAGE_A(0, 0); WSTAGE_B0(0, 0); WSTAGE_B1(0, 0);
  WSTAGE_A(1, 1);
  VM(2);
  BAR();

  for (int j = 0; j < NI-1; ++j){
    const int t = 2*j;
    /*ph1*/ WLDA8(0); WLDB4(0, 0); WSTAGE_B0(1, t+1); WSTAGE_B1(1, t+1); BAR(); WMF16(0); BAR();
    /*ph2*/ WLDB4(0, 1); VM(0); WSTAGE_A(0, t+2);                        BAR(); WMF16(1); BAR();
    /*ph3*/ WLDA8(1); WLDB4(1, 0); WSTAGE_B0(0, t+2); WSTAGE_B1(0, t+2); BAR(); WMF16(0); BAR();
    /*ph4*/ WLDB4(1, 1); VM(0); WSTAGE_A(1, t+3);                        BAR(); WMF16(1); BAR();
  }
  { // tail: tiles 2NI-2 (buf0) and 2NI-1 (buf1); only buf1-B stage remains
    const int t = 2*(NI-1);
    /*ph1*/ WLDA8(0); WLDB4(0, 0); WSTAGE_B0(1, t+1); WSTAGE_B1(1, t+1); BAR(); WMF16(0); BAR();
    /*ph2*/ WLDB4(0, 1); VM(0);                                          BAR(); WMF16(1); BAR();
    /*ph3*/ WLDA8(1); WLDB4(1, 0);                                       BAR(); WMF16(0); BAR();
    /*ph4*/ WLDB4(1, 1);                                                 BAR(); WMF16(1); BAR();
  }

  // epilogue: C/D map col = lane&15, row = g*4 + r
#pragma unroll
  for (int i = 0; i < 4; ++i)
#pragma unroll
    for (int jn = 0; jn < 4; ++jn){
      long off = (m0 + wm*64 + i*16 + g*4)*(long)N + n0 + wn*64 + jn*16 + c;
#pragma unroll
      for (int r = 0; r < 4; ++r)
        C[off + (long)r*N] = acc[i][jn][r];
    }
}

// ---------------- flash attention (verified r10: expf, THR=8, scalar pack) ----------------
__global__ __launch_bounds__(256) void attn_kernel(const ushort_t* __restrict__ Q,
                                                   const ushort_t* __restrict__ Kr,
                                                   const ushort_t* __restrict__ Vt,
                                                   ushort_t* __restrict__ O){
  const int tid = threadIdx.x;
  const int l = tid & 63, w = tid >> 6;
  const int g = l >> 4, c = l & 15;
  const int bh = blockIdx.x;
  const int qt = (int)gridDim.y - 1 - (int)blockIdx.y;
  const int b = bh >> 4, h = bh & 15;
  const int q0 = qt * 64;
  const int qw0 = q0 + w * 16;
  const int nt = qt + 1;

  __shared__ ushort_t k_lds[2][64*128];
  __shared__ ushort_t v_lds[2][128*64];
  __shared__ ushort_t p_lds[4][16*72];

  short8 qf[4];
  const long qbase = ((long)(b*2048 + qw0 + c))*2048 + h*128 + g*8;
#pragma unroll
  for (int ds = 0; ds < 4; ++ds) qf[ds] = *(const short8*)(Q + qbase + ds*32);

  const ushort_t* ksrc[4]; const ushort_t* vsrc[4];
  int kof[4], vof[4];
#pragma unroll
  for (int i = 0; i < 4; ++i){
    int q = i*256 + tid;
    int r = q >> 4, j = q & 15;
    ksrc[i] = Kr + ((long)(b*2048 + r))*2048 + h*128 + (j ^ (r & 7))*8;
    kof[i] = q*8;
    int d = q >> 3, jj = q & 7;
    vsrc[i] = Vt + ((long)(bh*128 + d))*2048 + (jj ^ (d & 7))*8;
    vof[i] = q*8;
  }

  f32x4 o[8] = {};
  float m = -1e30f, lsum = 0.f;
  const int sw = (c & 7) << 3;

#pragma unroll
  for (int i = 0; i < 4; ++i) gload_lds16(ksrc[i], &k_lds[0][kof[i]]);
#pragma unroll
  for (int i = 0; i < 4; ++i) gload_lds16(vsrc[i], &v_lds[0][vof[i]]);
  __syncthreads();

  for (int t = 0; t < nt; ++t){
    const int p = t & 1;
    if (t + 1 < nt){
#pragma unroll
      for (int i = 0; i < 4; ++i)
        gload_lds16(ksrc[i] + (long)(t+1)*64*2048, &k_lds[p^1][kof[i]]);
#pragma unroll
      for (int i = 0; i < 4; ++i)
        gload_lds16(vsrc[i] + (t+1)*64, &v_lds[p^1][vof[i]]);
    }
    const int kv0 = t*64;

    f32x4 s[4] = {};
    __builtin_amdgcn_s_setprio(1);
#pragma unroll
    for (int t4 = 0; t4 < 4; ++t4){
      const int row = 16*t4 + c;
#pragma unroll
      for (int ds = 0; ds < 4; ++ds){
        short8 kf = *(const short8*)&k_lds[p][(row*128 + ds*32 + g*8) ^ sw];
        s[t4] = __builtin_amdgcn_mfma_f32_16x16x32_bf16(kf, qf[ds], s[t4], 0, 0, 0);
      }
    }
    __builtin_amdgcn_s_setprio(0);
    if (kv0 + 63 > qw0){
      const int qg = qw0 + c;
#pragma unroll
      for (int t4 = 0; t4 < 4; ++t4)
#pragma unroll
        for (int r = 0; r < 4; ++r)
          if (kv0 + 16*t4 + 4*g + r > qg) s[t4][r] = -1e30f;
    }
    float tm = -1e30f;
#pragma unroll
    for (int t4 = 0; t4 < 4; ++t4)
      tm = fmaxf(tm, fmaxf(fmaxf(s[t4][0], s[t4][1]), fmaxf(s[t4][2], s[t4][3])));
    tm = fmaxf(tm, __shfl_xor(tm, 16, 64));
    tm = fmaxf(tm, __shfl_xor(tm, 32, 64));
    if (!__all(tm <= m + 8.f)){
      float mn = fmaxf(m, tm);
      float al = __expf(m - mn);
      m = mn;
      lsum *= al;
      float alr[4];
#pragma unroll
      for (int r = 0; r < 4; ++r) alr[r] = __shfl(al, 4*g + r, 64);
#pragma unroll
      for (int dt = 0; dt < 8; ++dt)
#pragma unroll
        for (int r = 0; r < 4; ++r) o[dt][r] *= alr[r];
    }
    float ps = 0.f;
#pragma unroll
    for (int t4 = 0; t4 < 4; ++t4)
#pragma unroll
      for (int r = 0; r < 4; ++r){ float pex = __expf(s[t4][r] - m); s[t4][r] = pex; ps += pex; }
    ps += __shfl_xor(ps, 16, 64);
    ps += __shfl_xor(ps, 32, 64);
    lsum += ps;
#pragma unroll
    for (int t4 = 0; t4 < 4; ++t4){
      uint2 pw;
      pw.x = (unsigned)f2bf(s[t4][0]) | ((unsigned)f2bf(s[t4][1]) << 16);
      pw.y = (unsigned)f2bf(s[t4][2]) | ((unsigned)f2bf(s[t4][3]) << 16);
      *reinterpret_cast<uint2*>(&p_lds[w][c*72 + 16*t4 + 4*g]) = pw;
    }
    __builtin_amdgcn_s_setprio(1);
#pragma unroll
    for (int kc = 0; kc < 2; ++kc){
      short8 pf = *(const short8*)&p_lds[w][c*72 + 32*kc + 8*g];
#pragma unroll
      for (int dt = 0; dt < 8; ++dt){
        short8 vf = *(const short8*)&v_lds[p][(((16*dt + c)*64) + kc*32 + g*8) ^ sw];
        o[dt] = __builtin_amdgcn_mfma_f32_16x16x32_bf16(pf, vf, o[dt], 0, 0, 0);
      }
    }
    __builtin_amdgcn_s_setprio(0);
    __syncthreads();
  }

  float inv = 1.f / lsum;
  float invr[4];
#pragma unroll
  for (int r = 0; r < 4; ++r) invr[r] = __shfl(inv, 4*g + r, 64);
  const long obase = ((long)(b*2048 + qw0 + g*4))*2048 + h*128 + c;
#pragma unroll
  for (int dt = 0; dt < 8; ++dt)
#pragma unroll
    for (int r = 0; r < 4; ++r)
      O[obase + (long)r*2048 + dt*16] = f2bf(o[dt][r] * invr[r]);
}

// ---------------- launcher ----------------
extern "C" void kernel_launch(void* const* d_in, const int* in_sizes, int n_in,
                              void* d_out, int out_size, void* d_ws, size_t ws_size,
                              hipStream_t stream){
  const float* x    = (const float*)d_in[0];
  const float* cosb = (const float*)d_in[1];
  const float* sinb = (const float*)d_in[2];
  const float* wq   = (const float*)d_in[3];
  const float* wk   = (const float*)d_in[4];
  const float* wv   = (const float*)d_in[5];
  const float* wo   = (const float*)d_in[6];
  float* out = (float*)d_out;

  const int S = 2048, DIM = 2048;
  const long MN = 4096;

  char* ws = (char*)d_ws;
  ushort_t* xb     = (ushort_t*)(ws);                 // 16MB
  ushort_t* wqkvb  = (ushort_t*)(ws + (16l<<20));     // 24MB
  ushort_t* wob    = (ushort_t*)(ws + (40l<<20));     // 8MB
  ushort_t* qstage = (ushort_t*)(ws + (48l<<20));     // 16MB
  ushort_t* kstage = (ushort_t*)(ws + (64l<<20));     // 16MB
  ushort_t* attnb  = (ushort_t*)(ws + (80l<<20));     // 16MB
  ushort_t* vt     = (ushort_t*)(ws + (96l<<20));     // 16MB -> 112MB total

  const long xn4 = MN*DIM/4, wn4 = (long)DIM*DIM/4;
  cast_bf16_kernel<<<(int)((xn4+255)/256), 256, 0, stream>>>(x, xb, xn4);
  cast4_bf16_kernel<<<dim3((int)((wn4+255)/256), 4), 256, 0, stream>>>(
      wq, wk, wv, wo,
      wqkvb, wqkvb + 4194304, wqkvb + 8388608, wob, wn4);

  gemm_qkv_8ph<<<(MN/256)*(6144/256), 512, 0, stream>>>(
      xb, wqkvb, qstage, kstage, vt, (int)(MN/256), DIM);

  const int ropeBlocks = (2*2048*16*16)/256;
  rope2_kernel<<<dim3(ropeBlocks, 2), 256, 0, stream>>>(qstage, kstage, cosb, sinb);
  attn_kernel<<<dim3(32, S/64), 256, 0, stream>>>(qstage, kstage, vt, attnb);
  gemm_wo_8ph<<<(MN/128)*(DIM/256), 512, 0, stream>>>(attnb, wob, out, (int)(MN/128), DIM, DIM);
}